// Round 18
// baseline (805.299 us; speedup 1.0000x reference)
//
#include <hip/hip_runtime.h>

// ---- problem constants ----
// BATCH=4096 HORIZON=64 HIST_DIM=256 HW=512 EMBED=96 LATENT=128
// out = [z_pred (4096,64,128) | x_pred (4096,64,32) | z_target (4096,64,128)] f32
#define XP_OFF 33554432L
#define ZT_OFF 41943040L

// padded bf16 weight layout in ws (row stride = ODD multiple of 64B lines -> no L2
// channel camping; verified r13: 831->631us from this alone):
#define W0_OFF 0
#define W1_OFF 147456
#define W2_OFF 425984
#define W3_OFF 704512
#define ZK_BYTE_OFF 1513472L

typedef __attribute__((ext_vector_type(8))) short bf16x8;   // 8 bf16 = 4 VGPRs
typedef __attribute__((ext_vector_type(4))) float f32x4;    // MFMA accum

__device__ __forceinline__ unsigned short f2bf(float f){
  union { float ff; unsigned int uu; } c; c.ff = f;
  unsigned int u = c.uu;
  return (unsigned short)((u + 0x7FFFu + ((u >> 16) & 1u)) >> 16);  // RNE
}

// ---------------- weight f32 -> bf16 convert (padded layout) ----------------
__global__ void cvt_kernel(const float* __restrict__ w0, const float* __restrict__ w1,
                           const float* __restrict__ w2, const float* __restrict__ w3,
                           unsigned short* __restrict__ o){
  int i = blockIdx.x * 256 + threadIdx.x;
  if (i < 131072){                                   // W0: 512x256
    int r = i >> 8, c = i & 255;
    o[W0_OFF + r*288 + c] = f2bf(w0[i]);
  } else if (i < 393216){                            // W1: 512x512
    int j = i - 131072; int r = j >> 9, c = j & 511;
    o[W1_OFF + r*544 + c] = f2bf(w1[j]);
  } else if (i < 655360){                            // W2: 512x512
    int j = i - 393216; int r = j >> 9, c = j & 511;
    o[W2_OFF + r*544 + c] = f2bf(w2[j]);
  } else if (i < 704512){                            // W3: 96x512
    int j = i - 655360; int r = j >> 9, c = j & 511;
    o[W3_OFF + r*544 + c] = f2bf(w3[j]);
  }
}

// ---------------- fused 4-layer encoder ----------------
// r18: r17 shell (8 waves/512thr, wave = 64 rows x 64 cols, NT=4 MT=4, a[4] upfront,
// padded W stride, 64KB LDS) with launch_bounds(512,2) -> 256-reg budget and DEPTH-3
// b-prefetch via 4 parity buffers (B0..B3, manual kc+=4 unroll, no rotation copies).
// Lookahead ~3 MFMA-halves (~930 cyc) >> L2 latency (~200-300) -> weight chain covered.
// Regs: acc 64 AGPR + b 4x16=64 + a 16 + addr ~25 = ~169 <= 256, no spill. 1 block/CU.
// MFMA swapped operands: D = mfma(Wfrag, ACTfrag) -> lane = (row m=ml, 4 consecutive cols).
template<int K, int WS, int NT, int MT>
__device__ __forceinline__ void gemm_tile(const unsigned short* __restrict__ W,
                                          const unsigned short* act,
                                          int lane, int ncol0, f32x4 (&acc)[NT][MT]){
  const int kl = (lane >> 4) << 3;   // k offset of this lane within 32-chunk
  const int ml = lane & 15;
  const unsigned short* wp = W + (ncol0 + ml)*WS + kl;   // W row (ncol0+ml), col kl
  constexpr int NK = K/32;           // 8 or 16 (divisible by 4)
  bf16x8 B0[NT], B1[NT], B2[NT], B3[NT];

  auto loadB = [&](bf16x8 (&bb)[NT], int kc){
#pragma unroll
    for (int nt = 0; nt < NT; ++nt)
      bb[nt] = *(const bf16x8*)(wp + nt*16*WS + kc*32);
  };
  auto half = [&](bf16x8 (&bb)[NT], int kc){
    const int kk = kc*32 + kl;
    bf16x8 a[MT];                                     // a ds_reads issued upfront
#pragma unroll
    for (int mt = 0; mt < MT; ++mt){
      int m = mt*16 + ml;
      int byt = ((m << 10) + (kk << 1)) ^ ((m & 7) << 4);
      a[mt] = *(const bf16x8*)((const char*)act + byt);
    }
#pragma unroll
    for (int mt = 0; mt < MT; ++mt)                   // mt-outer: progressive lgkmcnt
#pragma unroll
      for (int nt = 0; nt < NT; ++nt)
        acc[nt][mt] = __builtin_amdgcn_mfma_f32_16x16x32_bf16(bb[nt], a[mt], acc[nt][mt], 0, 0, 0);
  };

  loadB(B0, 0); loadB(B1, 1); loadB(B2, 2);   // prologue: 3 chunks in flight
#pragma unroll 1
  for (int kc = 0; kc < NK; kc += 4){
    loadB(B3, kc+3);                    half(B0, kc);
    if (kc + 4 < NK) loadB(B0, kc+4);   half(B1, kc+1);
    if (kc + 5 < NK) loadB(B1, kc+5);   half(B2, kc+2);
    if (kc + 6 < NK) loadB(B2, kc+6);   half(B3, kc+3);
  }
}

// epilogue: lane holds row m = mt*16+ml, cols n0..n0+3 (n0 = ncol0+nt*16+rl)
template<int NT, int MT>
__device__ __forceinline__ void epi_lds(f32x4 (&acc)[NT][MT], const float* __restrict__ bias,
                                        int ncol0, int lane, unsigned short* act){
  const int ml = lane & 15;
  const int rl = (lane >> 4) << 2;
#pragma unroll
  for (int nt = 0; nt < NT; ++nt){
    int n0 = ncol0 + nt*16 + rl;
    float4 bn = *(const float4*)(bias + n0);
#pragma unroll
    for (int mt = 0; mt < MT; ++mt){
      int m = mt*16 + ml;
      float v0 = acc[nt][mt][0] + bn.x; v0 = v0 > 0.f ? v0 : 0.f;
      float v1 = acc[nt][mt][1] + bn.y; v1 = v1 > 0.f ? v1 : 0.f;
      float v2 = acc[nt][mt][2] + bn.z; v2 = v2 > 0.f ? v2 : 0.f;
      float v3 = acc[nt][mt][3] + bn.w; v3 = v3 > 0.f ? v3 : 0.f;
      ushort4 p; p.x = f2bf(v0); p.y = f2bf(v1); p.z = f2bf(v2); p.w = f2bf(v3);
      int byt = ((m << 10) + (n0 << 1)) ^ ((m & 7) << 4);   // 8B-aligned, swizzle flips bit4
      *(ushort4*)((char*)act + byt) = p;
    }
  }
}

__global__ __launch_bounds__(512, 2) void enc_kernel(
    const float* __restrict__ histk, const float* __restrict__ histn,
    const unsigned short* __restrict__ wb,
    const float* __restrict__ b0, const float* __restrict__ b1,
    const float* __restrict__ b2, const float* __restrict__ b3,
    float* __restrict__ zk, float* __restrict__ out){
  __shared__ __align__(16) unsigned short act[64*512];   // 64 KB
  const int tid  = threadIdx.x;
  const int lane = tid & 63;
  const int wave = tid >> 6;           // 0..7, col group (64 cols each)
  const int blk  = blockIdx.x;
  const bool is_zk = (blk < 64);       // 4096 history_k rows = 64 blocks of 64
  const long r0 = (long)blk * 64;
  const float* __restrict__ src = is_zk ? (histk + r0*256) : (histn + (r0 - 4096)*256);
  const float4* src4 = (const float4*)src;

  // stage input tile (64x256 f32 -> bf16 LDS), emit "cur" state cols 224..255
#pragma unroll 4
  for (int j = 0; j < 8; ++j){
    int vidx = j*512 + tid;                      // 4096 float4 total
    float4 v = src4[vidx];
    int r  = vidx >> 6;
    int k0 = (vidx & 63) << 2;
    ushort4 p;
    p.x = f2bf(v.x); p.y = f2bf(v.y); p.z = f2bf(v.z); p.w = f2bf(v.w);
    int byt = ((r << 10) + (k0 << 1)) ^ ((r & 7) << 4);
    *(ushort4*)((char*)act + byt) = p;
    if (k0 >= 224){                              // hist[..., -32:] -> z[..., :32]
      long rg = r0 + r;
      int c = k0 - 224;
      if (is_zk) *(float4*)(zk + rg*128 + c) = v;
      else       *(float4*)(out + ZT_OFF + (rg - 4096)*128 + c) = v;
    }
  }
  __syncthreads();

  { // layer 0: 256 -> 512, wave owns cols [wave*64, wave*64+64)
    f32x4 acc[4][4];
#pragma unroll
    for (int i = 0; i < 4; ++i)
#pragma unroll
      for (int j = 0; j < 4; ++j) acc[i][j] = (f32x4){0.f,0.f,0.f,0.f};
    gemm_tile<256,288,4,4>(wb + W0_OFF, act, lane, wave*64, acc);
    __syncthreads();
    epi_lds<4,4>(acc, b0, wave*64, lane, act);
  }
  __syncthreads();
  { // layer 1: 512 -> 512
    f32x4 acc[4][4];
#pragma unroll
    for (int i = 0; i < 4; ++i)
#pragma unroll
      for (int j = 0; j < 4; ++j) acc[i][j] = (f32x4){0.f,0.f,0.f,0.f};
    gemm_tile<512,544,4,4>(wb + W1_OFF, act, lane, wave*64, acc);
    __syncthreads();
    epi_lds<4,4>(acc, b1, wave*64, lane, act);
  }
  __syncthreads();
  { // layer 2: 512 -> 512
    f32x4 acc[4][4];
#pragma unroll
    for (int i = 0; i < 4; ++i)
#pragma unroll
      for (int j = 0; j < 4; ++j) acc[i][j] = (f32x4){0.f,0.f,0.f,0.f};
    gemm_tile<512,544,4,4>(wb + W2_OFF, act, lane, wave*64, acc);
    __syncthreads();
    epi_lds<4,4>(acc, b2, wave*64, lane, act);
  }
  __syncthreads();
  { // layer 3: 512 -> 96 (no relu), waves 0..2 cover 96 cols (32 each), all 64 rows
    if (wave < 3){
      f32x4 acc[2][4];
#pragma unroll
      for (int i = 0; i < 2; ++i)
#pragma unroll
        for (int j = 0; j < 4; ++j) acc[i][j] = (f32x4){0.f,0.f,0.f,0.f};
      gemm_tile<512,544,2,4>(wb + W3_OFF, act, lane, wave*32, acc);
      const int ml = lane & 15, rl = (lane >> 4) << 2;
#pragma unroll
      for (int nt = 0; nt < 2; ++nt){
        int n0 = wave*32 + nt*16 + rl;           // embed col base (mult of 4)
        float4 bn = *(const float4*)(b3 + n0);
#pragma unroll
        for (int mt = 0; mt < 4; ++mt){
          int m = mt*16 + ml;
          long rg = r0 + m;
          float4 v;
          v.x = acc[nt][mt][0] + bn.x;
          v.y = acc[nt][mt][1] + bn.y;
          v.z = acc[nt][mt][2] + bn.z;
          v.w = acc[nt][mt][3] + bn.w;
          if (is_zk) *(float4*)(zk + rg*128 + 32 + n0) = v;
          else       *(float4*)(out + ZT_OFF + (rg - 4096)*128 + 32 + n0) = v;
        }
      }
    }
  }
}

// ---------------- fp32 linear scan: z <- z@A^T + u@B^T ----------------
// 4-way split accumulator (r17): breaks the 32-deep dependent FMA chain -> 8-deep x4.
__global__ __launch_bounds__(256, 2) void scan_kernel(
    const float* __restrict__ A, const float* __restrict__ B,
    const float* __restrict__ u, const float* __restrict__ zkv,
    float* __restrict__ out){
  __shared__ __align__(16) float zbuf[2][2][128];
  __shared__ __align__(16) float ubuf[1024];
  const int tid = threadIdx.x;
  const int lr  = tid >> 7;            // which of 2 batch rows
  const int l   = tid & 127;           // latent index
  const long row = (long)blockIdx.x * 2 + lr;

  float Ar[128];                       // A_W[l][0..127] -> fully static-indexed (VGPRs!)
  const float4* A4 = (const float4*)A;
#pragma unroll
  for (int j4 = 0; j4 < 32; ++j4){     // FULL unroll: static indices -> registers, no scratch
    float4 v = A4[l*32 + j4];
    Ar[4*j4] = v.x; Ar[4*j4+1] = v.y; Ar[4*j4+2] = v.z; Ar[4*j4+3] = v.w;
  }
  float Br[8];                         // B_W[l][0..7]
  {
    const float4* B4 = (const float4*)B;
    float4 v0 = B4[l*2], v1 = B4[l*2+1];
    Br[0]=v0.x; Br[1]=v0.y; Br[2]=v0.z; Br[3]=v0.w;
    Br[4]=v1.x; Br[5]=v1.y; Br[6]=v1.z; Br[7]=v1.w;
  }
  ((float4*)ubuf)[tid] = ((const float4*)(u + (long)blockIdx.x*1024))[tid];  // 2 rows of u_seq
  zbuf[0][lr][l] = zkv[row*128 + l];
  __syncthreads();

  const long zp = row*8192 + l;
  const long xp = XP_OFF + row*2048 + l;
  int cur = 0;
#pragma unroll 1
  for (int t = 0; t < 64; ++t){
    const float* zc = zbuf[cur][lr];
    float a0 = 0.f, a1 = 0.f, a2 = 0.f, a3 = 0.f;   // 4 independent chains
#pragma unroll
    for (int j4 = 0; j4 < 32; j4 += 4){
      float4 z0 = ((const float4*)zc)[j4+0];
      float4 z1 = ((const float4*)zc)[j4+1];
      float4 z2 = ((const float4*)zc)[j4+2];
      float4 z3 = ((const float4*)zc)[j4+3];
      a0 += Ar[4*j4+ 0]*z0.x + Ar[4*j4+ 1]*z0.y + Ar[4*j4+ 2]*z0.z + Ar[4*j4+ 3]*z0.w;
      a1 += Ar[4*j4+ 4]*z1.x + Ar[4*j4+ 5]*z1.y + Ar[4*j4+ 6]*z1.z + Ar[4*j4+ 7]*z1.w;
      a2 += Ar[4*j4+ 8]*z2.x + Ar[4*j4+ 9]*z2.y + Ar[4*j4+10]*z2.z + Ar[4*j4+11]*z2.w;
      a3 += Ar[4*j4+12]*z3.x + Ar[4*j4+13]*z3.y + Ar[4*j4+14]*z3.z + Ar[4*j4+15]*z3.w;
    }
    const float4* uu = (const float4*)(ubuf + lr*512 + t*8);
    float4 u0 = uu[0], u1 = uu[1];
    float ub = Br[0]*u0.x + Br[1]*u0.y + Br[2]*u0.z + Br[3]*u0.w
             + Br[4]*u1.x + Br[5]*u1.y + Br[6]*u1.z + Br[7]*u1.w;
    float acc = ((a0 + a1) + (a2 + a3)) + ub;
    zbuf[cur^1][lr][l] = acc;
    out[zp + t*128] = acc;                     // z_pred[row][t][l]
    if (l < 32) out[xp + t*32] = acc;          // x_pred[row][t][l]
    __syncthreads();
    cur ^= 1;
  }
}

extern "C" void kernel_launch(void* const* d_in, const int* in_sizes, int n_in,
                              void* d_out, int out_size, void* d_ws, size_t ws_size,
                              hipStream_t stream){
  const float* histk = (const float*)d_in[0];
  const float* useq  = (const float*)d_in[1];
  const float* histn = (const float*)d_in[2];
  const float* W0 = (const float*)d_in[3];
  const float* b0 = (const float*)d_in[4];
  const float* W1 = (const float*)d_in[5];
  const float* b1 = (const float*)d_in[6];
  const float* W2 = (const float*)d_in[7];
  const float* b2 = (const float*)d_in[8];
  const float* W3 = (const float*)d_in[9];
  const float* b3 = (const float*)d_in[10];
  const float* A  = (const float*)d_in[11];
  const float* B  = (const float*)d_in[12];
  float* out = (float*)d_out;

  // ws layout: [0, 1513472) padded bf16 weights; then z_k (4096x128 f32, 2 MB). ~3.5 MB
  unsigned short* wb = (unsigned short*)d_ws;
  float* zk = (float*)((char*)d_ws + ZK_BYTE_OFF);

  cvt_kernel <<<2752, 256, 0, stream>>>(W0, W1, W2, W3, wb);
  enc_kernel <<<4160, 512, 0, stream>>>(histk, histn, wb,
                                        b0, b1, b2, b3, zk, out);
  scan_kernel<<<2048, 256, 0, stream>>>(A, B, useq, zk, out);
}

// Round 19
// 657.492 us; speedup vs baseline: 1.2248x; 1.2248x over previous
//
#include <hip/hip_runtime.h>

// ---- problem constants ----
// BATCH=4096 HORIZON=64 HIST_DIM=256 HW=512 EMBED=96 LATENT=128
// out = [z_pred (4096,64,128) | x_pred (4096,64,32) | z_target (4096,64,128)] f32
#define XP_OFF 33554432L
#define ZT_OFF 41943040L

// r19 TILED weight layout in ws: chunk-contiguous in exact wave-load order.
// W'[c16][kc][ml][kl]: c16 = col>>4, kc = k>>5, ml = col&15, kl = k&31.
// One wave-load (16B/lane x 64 lanes) = ONE contiguous 1KB chunk (dense L2 streaming;
// r17's pattern was 16 scattered 64B segments/load -> measured only 10.2 TB/s of 34.5).
// Dense streaming also kills channel camping -> no odd-stride padding needed.
#define W0_OFF 0
#define W1_OFF 131072
#define W2_OFF 393216
#define W3_OFF 655360
#define ZK_BYTE_OFF 1409024L

typedef __attribute__((ext_vector_type(8))) short bf16x8;   // 8 bf16 = 4 VGPRs
typedef __attribute__((ext_vector_type(4))) float f32x4;    // MFMA accum

__device__ __forceinline__ unsigned short f2bf(float f){
  union { float ff; unsigned int uu; } c; c.ff = f;
  unsigned int u = c.uu;
  return (unsigned short)((u + 0x7FFFu + ((u >> 16) & 1u)) >> 16);  // RNE
}

// ---------------- weight f32 -> bf16 convert (tiled layout) ----------------
// out elem offset = base + ((col>>4)*NK + (k>>5))*512 + (col&15)*32 + (k&31)
__global__ void cvt_kernel(const float* __restrict__ w0, const float* __restrict__ w1,
                           const float* __restrict__ w2, const float* __restrict__ w3,
                           unsigned short* __restrict__ o){
  int i = blockIdx.x * 256 + threadIdx.x;
  if (i < 131072){                                   // W0: 512x256, NK=8
    int r = i >> 8, c = i & 255;
    o[W0_OFF + ((r >> 4)*8 + (c >> 5))*512 + (r & 15)*32 + (c & 31)] = f2bf(w0[i]);
  } else if (i < 393216){                            // W1: 512x512, NK=16
    int j = i - 131072; int r = j >> 9, c = j & 511;
    o[W1_OFF + ((r >> 4)*16 + (c >> 5))*512 + (r & 15)*32 + (c & 31)] = f2bf(w1[j]);
  } else if (i < 655360){                            // W2: 512x512, NK=16
    int j = i - 393216; int r = j >> 9, c = j & 511;
    o[W2_OFF + ((r >> 4)*16 + (c >> 5))*512 + (r & 15)*32 + (c & 31)] = f2bf(w2[j]);
  } else if (i < 704512){                            // W3: 96x512, NK=16
    int j = i - 655360; int r = j >> 9, c = j & 511;
    o[W3_OFF + ((r >> 4)*16 + (c >> 5))*512 + (r & 15)*32 + (c & 31)] = f2bf(w3[j]);
  }
}

// ---------------- fused 4-layer encoder ----------------
// r17 shell (MEASURED BEST 610us: 8 waves/512thr, wave = 64 rows x 64 cols, NT=4 MT=4,
// a[4] upfront, even/odd b0/b1 no-copy prefetch, launch_bounds(512,4), 64KB LDS,
// 2 blocks/CU) with ONE change: tiled weight layout -> each b-load is 1KB contiguous.
// Lane addr within chunk: (lane&15)*64 + (lane>>4)*16 bytes -- bijective over [0,1024).
// act LDS: 64 rows x 512 cols bf16, row stride 1024B, swizzle byte ^= (row&7)<<4.
// MFMA swapped operands: D = mfma(Wfrag, ACTfrag) -> lane = (row m=ml, 4 consecutive cols).
template<int K, int NT, int MT>
__device__ __forceinline__ void gemm_tile(const unsigned short* __restrict__ W,
                                          const unsigned short* act,
                                          int lane, int ncol0, f32x4 (&acc)[NT][MT]){
  const int kl = (lane >> 4) << 3;   // k offset of this lane within 32-chunk
  const int ml = lane & 15;
  constexpr int NK = K/32;           // 8 or 16 (always even)
  const unsigned short* wp = W + (ncol0 >> 4)*(NK*512) + ml*32 + kl;
  bf16x8 b0[NT], b1[NT];

  auto loadB = [&](bf16x8 (&bb)[NT], int kc){
#pragma unroll
    for (int nt = 0; nt < NT; ++nt)
      bb[nt] = *(const bf16x8*)(wp + nt*(NK*512) + kc*512);
  };
  auto half = [&](bf16x8 (&bb)[NT], int kc){
    const int kk = kc*32 + kl;
    bf16x8 a[MT];                                     // a ds_reads issued upfront
#pragma unroll
    for (int mt = 0; mt < MT; ++mt){
      int m = mt*16 + ml;
      int byt = ((m << 10) + (kk << 1)) ^ ((m & 7) << 4);
      a[mt] = *(const bf16x8*)((const char*)act + byt);
    }
#pragma unroll
    for (int mt = 0; mt < MT; ++mt)                   // mt-outer: progressive lgkmcnt
#pragma unroll
      for (int nt = 0; nt < NT; ++nt)
        acc[nt][mt] = __builtin_amdgcn_mfma_f32_16x16x32_bf16(bb[nt], a[mt], acc[nt][mt], 0, 0, 0);
  };

  loadB(b0, 0);
#pragma unroll 1
  for (int kc = 0; kc < NK; kc += 2){
    loadB(b1, kc+1);                  // prefetch kc+1 (in flight over MFMA(kc))
    half(b0, kc);
    if (kc + 2 < NK) loadB(b0, kc+2); // prefetch kc+2 (in flight over MFMA(kc+1))
    half(b1, kc+1);
  }
}

// epilogue: lane holds row m = mt*16+ml, cols n0..n0+3 (n0 = ncol0+nt*16+rl)
template<int NT, int MT>
__device__ __forceinline__ void epi_lds(f32x4 (&acc)[NT][MT], const float* __restrict__ bias,
                                        int ncol0, int lane, unsigned short* act){
  const int ml = lane & 15;
  const int rl = (lane >> 4) << 2;
#pragma unroll
  for (int nt = 0; nt < NT; ++nt){
    int n0 = ncol0 + nt*16 + rl;
    float4 bn = *(const float4*)(bias + n0);
#pragma unroll
    for (int mt = 0; mt < MT; ++mt){
      int m = mt*16 + ml;
      float v0 = acc[nt][mt][0] + bn.x; v0 = v0 > 0.f ? v0 : 0.f;
      float v1 = acc[nt][mt][1] + bn.y; v1 = v1 > 0.f ? v1 : 0.f;
      float v2 = acc[nt][mt][2] + bn.z; v2 = v2 > 0.f ? v2 : 0.f;
      float v3 = acc[nt][mt][3] + bn.w; v3 = v3 > 0.f ? v3 : 0.f;
      ushort4 p; p.x = f2bf(v0); p.y = f2bf(v1); p.z = f2bf(v2); p.w = f2bf(v3);
      int byt = ((m << 10) + (n0 << 1)) ^ ((m & 7) << 4);   // 8B-aligned, swizzle flips bit4
      *(ushort4*)((char*)act + byt) = p;
    }
  }
}

__global__ __launch_bounds__(512, 4) void enc_kernel(
    const float* __restrict__ histk, const float* __restrict__ histn,
    const unsigned short* __restrict__ wb,
    const float* __restrict__ b0, const float* __restrict__ b1,
    const float* __restrict__ b2, const float* __restrict__ b3,
    float* __restrict__ zk, float* __restrict__ out){
  __shared__ __align__(16) unsigned short act[64*512];   // 64 KB -> 2 blocks/CU
  const int tid  = threadIdx.x;
  const int lane = tid & 63;
  const int wave = tid >> 6;           // 0..7, col group (64 cols each)
  const int blk  = blockIdx.x;
  const bool is_zk = (blk < 64);       // 4096 history_k rows = 64 blocks of 64
  const long r0 = (long)blk * 64;
  const float* __restrict__ src = is_zk ? (histk + r0*256) : (histn + (r0 - 4096)*256);
  const float4* src4 = (const float4*)src;

  // stage input tile (64x256 f32 -> bf16 LDS), emit "cur" state cols 224..255
#pragma unroll 4
  for (int j = 0; j < 8; ++j){
    int vidx = j*512 + tid;                      // 4096 float4 total
    float4 v = src4[vidx];
    int r  = vidx >> 6;
    int k0 = (vidx & 63) << 2;
    ushort4 p;
    p.x = f2bf(v.x); p.y = f2bf(v.y); p.z = f2bf(v.z); p.w = f2bf(v.w);
    int byt = ((r << 10) + (k0 << 1)) ^ ((r & 7) << 4);
    *(ushort4*)((char*)act + byt) = p;
    if (k0 >= 224){                              // hist[..., -32:] -> z[..., :32]
      long rg = r0 + r;
      int c = k0 - 224;
      if (is_zk) *(float4*)(zk + rg*128 + c) = v;
      else       *(float4*)(out + ZT_OFF + (rg - 4096)*128 + c) = v;
    }
  }
  __syncthreads();

  { // layer 0: 256 -> 512, wave owns cols [wave*64, wave*64+64)
    f32x4 acc[4][4];
#pragma unroll
    for (int i = 0; i < 4; ++i)
#pragma unroll
      for (int j = 0; j < 4; ++j) acc[i][j] = (f32x4){0.f,0.f,0.f,0.f};
    gemm_tile<256,4,4>(wb + W0_OFF, act, lane, wave*64, acc);
    __syncthreads();
    epi_lds<4,4>(acc, b0, wave*64, lane, act);
  }
  __syncthreads();
  { // layer 1: 512 -> 512
    f32x4 acc[4][4];
#pragma unroll
    for (int i = 0; i < 4; ++i)
#pragma unroll
      for (int j = 0; j < 4; ++j) acc[i][j] = (f32x4){0.f,0.f,0.f,0.f};
    gemm_tile<512,4,4>(wb + W1_OFF, act, lane, wave*64, acc);
    __syncthreads();
    epi_lds<4,4>(acc, b1, wave*64, lane, act);
  }
  __syncthreads();
  { // layer 2: 512 -> 512
    f32x4 acc[4][4];
#pragma unroll
    for (int i = 0; i < 4; ++i)
#pragma unroll
      for (int j = 0; j < 4; ++j) acc[i][j] = (f32x4){0.f,0.f,0.f,0.f};
    gemm_tile<512,4,4>(wb + W2_OFF, act, lane, wave*64, acc);
    __syncthreads();
    epi_lds<4,4>(acc, b2, wave*64, lane, act);
  }
  __syncthreads();
  { // layer 3: 512 -> 96 (no relu), waves 0..2 cover 96 cols (32 each), all 64 rows
    if (wave < 3){
      f32x4 acc[2][4];
#pragma unroll
      for (int i = 0; i < 2; ++i)
#pragma unroll
        for (int j = 0; j < 4; ++j) acc[i][j] = (f32x4){0.f,0.f,0.f,0.f};
      gemm_tile<512,2,4>(wb + W3_OFF, act, lane, wave*32, acc);
      const int ml = lane & 15, rl = (lane >> 4) << 2;
#pragma unroll
      for (int nt = 0; nt < 2; ++nt){
        int n0 = wave*32 + nt*16 + rl;           // embed col base (mult of 4)
        float4 bn = *(const float4*)(b3 + n0);
#pragma unroll
        for (int mt = 0; mt < 4; ++mt){
          int m = mt*16 + ml;
          long rg = r0 + m;
          float4 v;
          v.x = acc[nt][mt][0] + bn.x;
          v.y = acc[nt][mt][1] + bn.y;
          v.z = acc[nt][mt][2] + bn.z;
          v.w = acc[nt][mt][3] + bn.w;
          if (is_zk) *(float4*)(zk + rg*128 + 32 + n0) = v;
          else       *(float4*)(out + ZT_OFF + (rg - 4096)*128 + 32 + n0) = v;
        }
      }
    }
  }
}

// ---------------- fp32 linear scan: z <- z@A^T + u@B^T ----------------
// 4-way split accumulator (r17): breaks the 32-deep dependent FMA chain -> 8-deep x4.
__global__ __launch_bounds__(256, 2) void scan_kernel(
    const float* __restrict__ A, const float* __restrict__ B,
    const float* __restrict__ u, const float* __restrict__ zkv,
    float* __restrict__ out){
  __shared__ __align__(16) float zbuf[2][2][128];
  __shared__ __align__(16) float ubuf[1024];
  const int tid = threadIdx.x;
  const int lr  = tid >> 7;            // which of 2 batch rows
  const int l   = tid & 127;           // latent index
  const long row = (long)blockIdx.x * 2 + lr;

  float Ar[128];                       // A_W[l][0..127] -> fully static-indexed (VGPRs!)
  const float4* A4 = (const float4*)A;
#pragma unroll
  for (int j4 = 0; j4 < 32; ++j4){     // FULL unroll: static indices -> registers, no scratch
    float4 v = A4[l*32 + j4];
    Ar[4*j4] = v.x; Ar[4*j4+1] = v.y; Ar[4*j4+2] = v.z; Ar[4*j4+3] = v.w;
  }
  float Br[8];                         // B_W[l][0..7]
  {
    const float4* B4 = (const float4*)B;
    float4 v0 = B4[l*2], v1 = B4[l*2+1];
    Br[0]=v0.x; Br[1]=v0.y; Br[2]=v0.z; Br[3]=v0.w;
    Br[4]=v1.x; Br[5]=v1.y; Br[6]=v1.z; Br[7]=v1.w;
  }
  ((float4*)ubuf)[tid] = ((const float4*)(u + (long)blockIdx.x*1024))[tid];  // 2 rows of u_seq
  zbuf[0][lr][l] = zkv[row*128 + l];
  __syncthreads();

  const long zp = row*8192 + l;
  const long xp = XP_OFF + row*2048 + l;
  int cur = 0;
#pragma unroll 1
  for (int t = 0; t < 64; ++t){
    const float* zc = zbuf[cur][lr];
    float a0 = 0.f, a1 = 0.f, a2 = 0.f, a3 = 0.f;   // 4 independent chains
#pragma unroll
    for (int j4 = 0; j4 < 32; j4 += 4){
      float4 z0 = ((const float4*)zc)[j4+0];
      float4 z1 = ((const float4*)zc)[j4+1];
      float4 z2 = ((const float4*)zc)[j4+2];
      float4 z3 = ((const float4*)zc)[j4+3];
      a0 += Ar[4*j4+ 0]*z0.x + Ar[4*j4+ 1]*z0.y + Ar[4*j4+ 2]*z0.z + Ar[4*j4+ 3]*z0.w;
      a1 += Ar[4*j4+ 4]*z1.x + Ar[4*j4+ 5]*z1.y + Ar[4*j4+ 6]*z1.z + Ar[4*j4+ 7]*z1.w;
      a2 += Ar[4*j4+ 8]*z2.x + Ar[4*j4+ 9]*z2.y + Ar[4*j4+10]*z2.z + Ar[4*j4+11]*z2.w;
      a3 += Ar[4*j4+12]*z3.x + Ar[4*j4+13]*z3.y + Ar[4*j4+14]*z3.z + Ar[4*j4+15]*z3.w;
    }
    const float4* uu = (const float4*)(ubuf + lr*512 + t*8);
    float4 u0 = uu[0], u1 = uu[1];
    float ub = Br[0]*u0.x + Br[1]*u0.y + Br[2]*u0.z + Br[3]*u0.w
             + Br[4]*u1.x + Br[5]*u1.y + Br[6]*u1.z + Br[7]*u1.w;
    float acc = ((a0 + a1) + (a2 + a3)) + ub;
    zbuf[cur^1][lr][l] = acc;
    out[zp + t*128] = acc;                     // z_pred[row][t][l]
    if (l < 32) out[xp + t*32] = acc;          // x_pred[row][t][l]
    __syncthreads();
    cur ^= 1;
  }
}

extern "C" void kernel_launch(void* const* d_in, const int* in_sizes, int n_in,
                              void* d_out, int out_size, void* d_ws, size_t ws_size,
                              hipStream_t stream){
  const float* histk = (const float*)d_in[0];
  const float* useq  = (const float*)d_in[1];
  const float* histn = (const float*)d_in[2];
  const float* W0 = (const float*)d_in[3];
  const float* b0 = (const float*)d_in[4];
  const float* W1 = (const float*)d_in[5];
  const float* b1 = (const float*)d_in[6];
  const float* W2 = (const float*)d_in[7];
  const float* b2 = (const float*)d_in[8];
  const float* W3 = (const float*)d_in[9];
  const float* b3 = (const float*)d_in[10];
  const float* A  = (const float*)d_in[11];
  const float* B  = (const float*)d_in[12];
  float* out = (float*)d_out;

  // ws layout: [0, 1409024) tiled bf16 weights; then z_k (4096x128 f32, 2 MB). ~3.4 MB
  unsigned short* wb = (unsigned short*)d_ws;
  float* zk = (float*)((char*)d_ws + ZK_BYTE_OFF);

  cvt_kernel <<<2752, 256, 0, stream>>>(W0, W1, W2, W3, wb);
  enc_kernel <<<4160, 512, 0, stream>>>(histk, histn, wb,
                                        b0, b1, b2, b3, zk, out);
  scan_kernel<<<2048, 256, 0, stream>>>(A, B, useq, zk, out);
}

// Round 20
// 638.512 us; speedup vs baseline: 1.2612x; 1.0297x over previous
//
#include <hip/hip_runtime.h>

// ---- problem constants ----
// BATCH=4096 HORIZON=64 HIST_DIM=256 HW=512 EMBED=96 LATENT=128
// out = [z_pred (4096,64,128) | x_pred (4096,64,32) | z_target (4096,64,128)] f32
#define XP_OFF 33554432L
#define ZT_OFF 41943040L

// TILED weight layout (r19, verified 610->548us): chunk-contiguous in exact wave-load
// order. W'[c16][kc][ml][kl]; one wave-load = one contiguous 1KB chunk (dense L2 stream).
#define W0_OFF 0
#define W1_OFF 131072
#define W2_OFF 393216
#define W3_OFF 655360
#define ZK_BYTE_OFF 1409024L

typedef __attribute__((ext_vector_type(8))) short bf16x8;   // 8 bf16 = 4 VGPRs
typedef __attribute__((ext_vector_type(4))) float f32x4;    // MFMA accum

__device__ __forceinline__ unsigned short f2bf(float f){
  union { float ff; unsigned int uu; } c; c.ff = f;
  unsigned int u = c.uu;
  return (unsigned short)((u + 0x7FFFu + ((u >> 16) & 1u)) >> 16);  // RNE
}

// r20: HW packed convert -- 2 f32 -> 2 bf16 (RNE) in ONE VALU op (vs 8 ops via f2bf).
__device__ __forceinline__ unsigned int cvtpk(float lo, float hi){
  unsigned int r;
  asm("v_cvt_pk_bf16_f32 %0, %1, %2" : "=v"(r) : "v"(lo), "v"(hi));
  return r;   // bits[15:0]=bf16(lo), bits[31:16]=bf16(hi)
}

// ---------------- weight f32 -> bf16 convert (tiled layout) ----------------
__global__ void cvt_kernel(const float* __restrict__ w0, const float* __restrict__ w1,
                           const float* __restrict__ w2, const float* __restrict__ w3,
                           unsigned short* __restrict__ o){
  int i = blockIdx.x * 256 + threadIdx.x;
  if (i < 131072){                                   // W0: 512x256, NK=8
    int r = i >> 8, c = i & 255;
    o[W0_OFF + ((r >> 4)*8 + (c >> 5))*512 + (r & 15)*32 + (c & 31)] = f2bf(w0[i]);
  } else if (i < 393216){                            // W1: 512x512, NK=16
    int j = i - 131072; int r = j >> 9, c = j & 511;
    o[W1_OFF + ((r >> 4)*16 + (c >> 5))*512 + (r & 15)*32 + (c & 31)] = f2bf(w1[j]);
  } else if (i < 655360){                            // W2: 512x512, NK=16
    int j = i - 393216; int r = j >> 9, c = j & 511;
    o[W2_OFF + ((r >> 4)*16 + (c >> 5))*512 + (r & 15)*32 + (c & 31)] = f2bf(w2[j]);
  } else if (i < 704512){                            // W3: 96x512, NK=16
    int j = i - 655360; int r = j >> 9, c = j & 511;
    o[W3_OFF + ((r >> 4)*16 + (c >> 5))*512 + (r & 15)*32 + (c & 31)] = f2bf(w3[j]);
  }
}

// ---------------- fused 4-layer encoder ----------------
// r19 shell (MEASURED BEST 548us) + r20 changes: (1) v_cvt_pk_bf16_f32 in staging and
// epilogue; (2) next layer's first b-chunk preloaded BEFORE the barrier (L2 latency
// hides under other waves' epilogue + barrier wait).
template<int K, int NT>
__device__ __forceinline__ void preloadB(const unsigned short* __restrict__ W,
                                         int lane, int ncol0, bf16x8 (&bb)[NT]){
  const int kl = (lane >> 4) << 3;
  const int ml = lane & 15;
  constexpr int NK = K/32;
  const unsigned short* wp = W + (ncol0 >> 4)*(NK*512) + ml*32 + kl;
#pragma unroll
  for (int nt = 0; nt < NT; ++nt)
    bb[nt] = *(const bf16x8*)(wp + nt*(NK*512));
}

template<int K, int NT, int MT>
__device__ __forceinline__ void gemm_tile(const unsigned short* __restrict__ W,
                                          const unsigned short* act,
                                          int lane, int ncol0, f32x4 (&acc)[NT][MT],
                                          bf16x8 (&b0)[NT]){   // b0 = preloaded chunk 0
  const int kl = (lane >> 4) << 3;   // k offset of this lane within 32-chunk
  const int ml = lane & 15;
  constexpr int NK = K/32;           // 8 or 16 (always even)
  const unsigned short* wp = W + (ncol0 >> 4)*(NK*512) + ml*32 + kl;
  bf16x8 b1[NT];

  auto loadB = [&](bf16x8 (&bb)[NT], int kc){
#pragma unroll
    for (int nt = 0; nt < NT; ++nt)
      bb[nt] = *(const bf16x8*)(wp + nt*(NK*512) + kc*512);
  };
  auto half = [&](bf16x8 (&bb)[NT], int kc){
    const int kk = kc*32 + kl;
    bf16x8 a[MT];                                     // a ds_reads issued upfront
#pragma unroll
    for (int mt = 0; mt < MT; ++mt){
      int m = mt*16 + ml;
      int byt = ((m << 10) + (kk << 1)) ^ ((m & 7) << 4);
      a[mt] = *(const bf16x8*)((const char*)act + byt);
    }
#pragma unroll
    for (int mt = 0; mt < MT; ++mt)                   // mt-outer: progressive lgkmcnt
#pragma unroll
      for (int nt = 0; nt < NT; ++nt)
        acc[nt][mt] = __builtin_amdgcn_mfma_f32_16x16x32_bf16(bb[nt], a[mt], acc[nt][mt], 0, 0, 0);
  };

#pragma unroll 1
  for (int kc = 0; kc < NK; kc += 2){
    loadB(b1, kc+1);                  // prefetch kc+1 (in flight over MFMA(kc))
    half(b0, kc);
    if (kc + 2 < NK) loadB(b0, kc+2); // prefetch kc+2 (in flight over MFMA(kc+1))
    half(b1, kc+1);
  }
}

// epilogue: lane holds row m = mt*16+ml, cols n0..n0+3 (n0 = ncol0+nt*16+rl)
template<int NT, int MT>
__device__ __forceinline__ void epi_lds(f32x4 (&acc)[NT][MT], const float* __restrict__ bias,
                                        int ncol0, int lane, unsigned short* act){
  const int ml = lane & 15;
  const int rl = (lane >> 4) << 2;
#pragma unroll
  for (int nt = 0; nt < NT; ++nt){
    int n0 = ncol0 + nt*16 + rl;
    float4 bn = *(const float4*)(bias + n0);
#pragma unroll
    for (int mt = 0; mt < MT; ++mt){
      int m = mt*16 + ml;
      float v0 = acc[nt][mt][0] + bn.x; v0 = v0 > 0.f ? v0 : 0.f;
      float v1 = acc[nt][mt][1] + bn.y; v1 = v1 > 0.f ? v1 : 0.f;
      float v2 = acc[nt][mt][2] + bn.z; v2 = v2 > 0.f ? v2 : 0.f;
      float v3 = acc[nt][mt][3] + bn.w; v3 = v3 > 0.f ? v3 : 0.f;
      uint2 pk; pk.x = cvtpk(v0, v1); pk.y = cvtpk(v2, v3);   // 2 VALU ops (was 16)
      int byt = ((m << 10) + (n0 << 1)) ^ ((m & 7) << 4);     // 8B-aligned
      *(uint2*)((char*)act + byt) = pk;
    }
  }
}

__global__ __launch_bounds__(512, 4) void enc_kernel(
    const float* __restrict__ histk, const float* __restrict__ histn,
    const unsigned short* __restrict__ wb,
    const float* __restrict__ b0, const float* __restrict__ b1,
    const float* __restrict__ b2, const float* __restrict__ b3,
    float* __restrict__ zk, float* __restrict__ out){
  __shared__ __align__(16) unsigned short act[64*512];   // 64 KB -> 2 blocks/CU
  const int tid  = threadIdx.x;
  const int lane = tid & 63;
  const int wave = tid >> 6;           // 0..7, col group (64 cols each)
  const int blk  = blockIdx.x;
  const bool is_zk = (blk < 64);       // 4096 history_k rows = 64 blocks of 64
  const long r0 = (long)blk * 64;
  const float* __restrict__ src = is_zk ? (histk + r0*256) : (histn + (r0 - 4096)*256);
  const float4* src4 = (const float4*)src;

  // stage input tile (64x256 f32 -> bf16 LDS), emit "cur" state cols 224..255
#pragma unroll 4
  for (int j = 0; j < 8; ++j){
    int vidx = j*512 + tid;                      // 4096 float4 total
    float4 v = src4[vidx];
    int r  = vidx >> 6;
    int k0 = (vidx & 63) << 2;
    uint2 pk; pk.x = cvtpk(v.x, v.y); pk.y = cvtpk(v.z, v.w);
    int byt = ((r << 10) + (k0 << 1)) ^ ((r & 7) << 4);
    *(uint2*)((char*)act + byt) = pk;
    if (k0 >= 224){                              // hist[..., -32:] -> z[..., :32]
      long rg = r0 + r;
      int c = k0 - 224;
      if (is_zk) *(float4*)(zk + rg*128 + c) = v;
      else       *(float4*)(out + ZT_OFF + (rg - 4096)*128 + c) = v;
    }
  }
  bf16x8 pb[4];                                  // cross-layer preload buffer
  preloadB<256,4>(wb + W0_OFF, lane, wave*64, pb);
  __syncthreads();

  { // layer 0: 256 -> 512, wave owns cols [wave*64, wave*64+64)
    f32x4 acc[4][4];
#pragma unroll
    for (int i = 0; i < 4; ++i)
#pragma unroll
      for (int j = 0; j < 4; ++j) acc[i][j] = (f32x4){0.f,0.f,0.f,0.f};
    gemm_tile<256,4,4>(wb + W0_OFF, act, lane, wave*64, acc, pb);
    __syncthreads();
    epi_lds<4,4>(acc, b0, wave*64, lane, act);
  }
  preloadB<512,4>(wb + W1_OFF, lane, wave*64, pb);  // hide L2 latency under barrier
  __syncthreads();
  { // layer 1: 512 -> 512
    f32x4 acc[4][4];
#pragma unroll
    for (int i = 0; i < 4; ++i)
#pragma unroll
      for (int j = 0; j < 4; ++j) acc[i][j] = (f32x4){0.f,0.f,0.f,0.f};
    gemm_tile<512,4,4>(wb + W1_OFF, act, lane, wave*64, acc, pb);
    __syncthreads();
    epi_lds<4,4>(acc, b1, wave*64, lane, act);
  }
  preloadB<512,4>(wb + W2_OFF, lane, wave*64, pb);
  __syncthreads();
  { // layer 2: 512 -> 512
    f32x4 acc[4][4];
#pragma unroll
    for (int i = 0; i < 4; ++i)
#pragma unroll
      for (int j = 0; j < 4; ++j) acc[i][j] = (f32x4){0.f,0.f,0.f,0.f};
    gemm_tile<512,4,4>(wb + W2_OFF, act, lane, wave*64, acc, pb);
    __syncthreads();
    epi_lds<4,4>(acc, b2, wave*64, lane, act);
  }
  bf16x8 pb3[2];
  if (wave < 3) preloadB<512,2>(wb + W3_OFF, lane, wave*32, pb3);
  __syncthreads();
  { // layer 3: 512 -> 96 (no relu), waves 0..2 cover 96 cols (32 each), all 64 rows
    if (wave < 3){
      f32x4 acc[2][4];
#pragma unroll
      for (int i = 0; i < 2; ++i)
#pragma unroll
        for (int j = 0; j < 4; ++j) acc[i][j] = (f32x4){0.f,0.f,0.f,0.f};
      gemm_tile<512,2,4>(wb + W3_OFF, act, lane, wave*32, acc, pb3);
      const int ml = lane & 15, rl = (lane >> 4) << 2;
#pragma unroll
      for (int nt = 0; nt < 2; ++nt){
        int n0 = wave*32 + nt*16 + rl;           // embed col base (mult of 4)
        float4 bn = *(const float4*)(b3 + n0);
#pragma unroll
        for (int mt = 0; mt < 4; ++mt){
          int m = mt*16 + ml;
          long rg = r0 + m;
          float4 v;
          v.x = acc[nt][mt][0] + bn.x;
          v.y = acc[nt][mt][1] + bn.y;
          v.z = acc[nt][mt][2] + bn.z;
          v.w = acc[nt][mt][3] + bn.w;
          if (is_zk) *(float4*)(zk + rg*128 + 32 + n0) = v;
          else       *(float4*)(out + ZT_OFF + (rg - 4096)*128 + 32 + n0) = v;
        }
      }
    }
  }
}

// ---------------- fp32 linear scan: z <- z@A^T + u@B^T ----------------
// 4-way split accumulator (r17): breaks the 32-deep dependent FMA chain -> 8-deep x4.
__global__ __launch_bounds__(256, 2) void scan_kernel(
    const float* __restrict__ A, const float* __restrict__ B,
    const float* __restrict__ u, const float* __restrict__ zkv,
    float* __restrict__ out){
  __shared__ __align__(16) float zbuf[2][2][128];
  __shared__ __align__(16) float ubuf[1024];
  const int tid = threadIdx.x;
  const int lr  = tid >> 7;            // which of 2 batch rows
  const int l   = tid & 127;           // latent index
  const long row = (long)blockIdx.x * 2 + lr;

  float Ar[128];                       // A_W[l][0..127] -> fully static-indexed (VGPRs!)
  const float4* A4 = (const float4*)A;
#pragma unroll
  for (int j4 = 0; j4 < 32; ++j4){     // FULL unroll: static indices -> registers, no scratch
    float4 v = A4[l*32 + j4];
    Ar[4*j4] = v.x; Ar[4*j4+1] = v.y; Ar[4*j4+2] = v.z; Ar[4*j4+3] = v.w;
  }
  float Br[8];                         // B_W[l][0..7]
  {
    const float4* B4 = (const float4*)B;
    float4 v0 = B4[l*2], v1 = B4[l*2+1];
    Br[0]=v0.x; Br[1]=v0.y; Br[2]=v0.z; Br[3]=v0.w;
    Br[4]=v1.x; Br[5]=v1.y; Br[6]=v1.z; Br[7]=v1.w;
  }
  ((float4*)ubuf)[tid] = ((const float4*)(u + (long)blockIdx.x*1024))[tid];  // 2 rows of u_seq
  zbuf[0][lr][l] = zkv[row*128 + l];
  __syncthreads();

  const long zp = row*8192 + l;
  const long xp = XP_OFF + row*2048 + l;
  int cur = 0;
#pragma unroll 1
  for (int t = 0; t < 64; ++t){
    const float* zc = zbuf[cur][lr];
    float a0 = 0.f, a1 = 0.f, a2 = 0.f, a3 = 0.f;   // 4 independent chains
#pragma unroll
    for (int j4 = 0; j4 < 32; j4 += 4){
      float4 z0 = ((const float4*)zc)[j4+0];
      float4 z1 = ((const float4*)zc)[j4+1];
      float4 z2 = ((const float4*)zc)[j4+2];
      float4 z3 = ((const float4*)zc)[j4+3];
      a0 += Ar[4*j4+ 0]*z0.x + Ar[4*j4+ 1]*z0.y + Ar[4*j4+ 2]*z0.z + Ar[4*j4+ 3]*z0.w;
      a1 += Ar[4*j4+ 4]*z1.x + Ar[4*j4+ 5]*z1.y + Ar[4*j4+ 6]*z1.z + Ar[4*j4+ 7]*z1.w;
      a2 += Ar[4*j4+ 8]*z2.x + Ar[4*j4+ 9]*z2.y + Ar[4*j4+10]*z2.z + Ar[4*j4+11]*z2.w;
      a3 += Ar[4*j4+12]*z3.x + Ar[4*j4+13]*z3.y + Ar[4*j4+14]*z3.z + Ar[4*j4+15]*z3.w;
    }
    const float4* uu = (const float4*)(ubuf + lr*512 + t*8);
    float4 u0 = uu[0], u1 = uu[1];
    float ub = Br[0]*u0.x + Br[1]*u0.y + Br[2]*u0.z + Br[3]*u0.w
             + Br[4]*u1.x + Br[5]*u1.y + Br[6]*u1.z + Br[7]*u1.w;
    float acc = ((a0 + a1) + (a2 + a3)) + ub;
    zbuf[cur^1][lr][l] = acc;
    out[zp + t*128] = acc;                     // z_pred[row][t][l]
    if (l < 32) out[xp + t*32] = acc;          // x_pred[row][t][l]
    __syncthreads();
    cur ^= 1;
  }
}

extern "C" void kernel_launch(void* const* d_in, const int* in_sizes, int n_in,
                              void* d_out, int out_size, void* d_ws, size_t ws_size,
                              hipStream_t stream){
  const float* histk = (const float*)d_in[0];
  const float* useq  = (const float*)d_in[1];
  const float* histn = (const float*)d_in[2];
  const float* W0 = (const float*)d_in[3];
  const float* b0 = (const float*)d_in[4];
  const float* W1 = (const float*)d_in[5];
  const float* b1 = (const float*)d_in[6];
  const float* W2 = (const float*)d_in[7];
  const float* b2 = (const float*)d_in[8];
  const float* W3 = (const float*)d_in[9];
  const float* b3 = (const float*)d_in[10];
  const float* A  = (const float*)d_in[11];
  const float* B  = (const float*)d_in[12];
  float* out = (float*)d_out;

  // ws layout: [0, 1409024) tiled bf16 weights; then z_k (4096x128 f32, 2 MB). ~3.4 MB
  unsigned short* wb = (unsigned short*)d_ws;
  float* zk = (float*)((char*)d_ws + ZK_BYTE_OFF);

  cvt_kernel <<<2752, 256, 0, stream>>>(W0, W1, W2, W3, wb);
  enc_kernel <<<4160, 512, 0, stream>>>(histk, histn, wb,
                                        b0, b1, b2, b3, zk, out);
  scan_kernel<<<2048, 256, 0, stream>>>(A, B, useq, zk, out);
}